// Round 4
// baseline (2901.235 us; speedup 1.0000x reference)
//
#include <hip/hip_runtime.h>
#include <stdint.h>

#define SEQ   16384
#define EMB   50
#define HID   300
#define G4    1200
#define NTAG  20
#define START 18
#define STOPT 19
#define NEGV  -10000.0f
#define NC    64
#define CH    256   // SEQ / NC (viterbi chunking)

#define CHK   128   // LSTM chunk length
#define NCHK  128   // chunks per direction
#define BURN  64    // burn-in steps (f^64 <= f16 eps for any plausible forget gate)

__device__ __forceinline__ float rcp_fast(float x){ return __builtin_amdgcn_rcpf(x); }
__device__ __forceinline__ float sigmoidf_(float x){ return rcp_fast(1.f + __expf(-x)); }
__device__ __forceinline__ float tanhf_fast(float x){
    float e = __expf(-2.f * fabsf(x));
    float r = (1.f - e) * rcp_fast(1.f + e);
    return copysignf(r, x);
}

// ---- f16 helpers (recurrent path is f16: more mantissa than bf16) ----------
typedef _Float16 half2v __attribute__((ext_vector_type(2)));

__device__ __forceinline__ uint16_t f16_bits(float x){
    union { _Float16 h; uint16_t u; } v; v.h = (_Float16)x; return v.u;
}
__device__ __forceinline__ float f16_to_f32(uint16_t u){
    union { _Float16 h; uint16_t u; } v; v.u = u; return (float)v.h;
}
__device__ __forceinline__ uint32_t pack_f16x2(float a, float b){
    return (uint32_t)f16_bits(a) | ((uint32_t)f16_bits(b) << 16);
}
// acc += w.lo*h.lo + w.hi*h.hi  (one v_dot2_f32_f16 when available)
__device__ __forceinline__ float dot2f16(uint32_t w, uint32_t h, float acc){
    union { uint32_t u; half2v v; } a, b; a.u = w; b.u = h;
#if __has_builtin(__builtin_amdgcn_fdot2)
    return __builtin_amdgcn_fdot2(a.v, b.v, acc, false);
#else
    acc = fmaf((float)a.v.x, (float)b.v.x, acc);
    return fmaf((float)a.v.y, (float)b.v.y, acc);
#endif
}

// ---------------------------------------------------------------------------
// Phase A: xg[d][t][1200] (f16) = emb[sent[t]] @ w_ih_d.T + b_ih_d + b_hh_d
// ---------------------------------------------------------------------------
__global__ __launch_bounds__(256) void xg_kernel(
    const int* __restrict__ sent, const float* __restrict__ embed,
    const float* __restrict__ w_ih_f, const float* __restrict__ b_ih_f, const float* __restrict__ b_hh_f,
    const float* __restrict__ w_ih_b, const float* __restrict__ b_ih_b, const float* __restrict__ b_hh_b,
    uint16_t* __restrict__ xg)
{
    const int tg = blockIdx.x / 16;
    const int rg = blockIdx.x % 16;
    const int d  = rg / 8;
    const int rbase = (rg % 8) * 150;
    const int t = tg * 256 + threadIdx.x;

    const float* w_ih = d ? w_ih_b : w_ih_f;
    const float* b_ih = d ? b_ih_b : b_ih_f;
    const float* b_hh = d ? b_hh_b : b_hh_f;

    const int idx = sent[t];
    float e[EMB];
    const float* ep = embed + (size_t)idx * EMB;
    #pragma unroll
    for (int c = 0; c < EMB; c += 2){
        float2 v = *(const float2*)(ep + c);
        e[c] = v.x; e[c+1] = v.y;
    }
    uint16_t* outp = xg + ((size_t)d * SEQ + t) * G4 + rbase;
    #pragma unroll 1
    for (int rr = 0; rr < 150; rr += 2){
        float acc[2];
        #pragma unroll
        for (int k = 0; k < 2; k++){
            const int row = rbase + rr + k;
            const float* wr = w_ih + (size_t)row * EMB;
            float a0 = 0.f, a1 = 0.f;
            #pragma unroll
            for (int c = 0; c < EMB; c += 2){
                a0 += e[c]   * wr[c];
                a1 += e[c+1] * wr[c+1];
            }
            acc[k] = a0 + a1 + b_ih[row] + b_hh[row];
        }
        *(uint32_t*)(outp + rr) = pack_f16x2(acc[0], acc[1]);
    }
}

// ---------------------------------------------------------------------------
// Prep: pack w_hh (f32 [1200][300]) -> wpk[d][kk][u][gate] (f16 pairs, k=2kk).
// Gate-interleaved: the LSTM loads one dwordx4 per (u,kk); coalesced per wave.
// ---------------------------------------------------------------------------
__global__ __launch_bounds__(256) void prep_w(
    const float* __restrict__ wf, const float* __restrict__ wb, uint32_t* __restrict__ wpk)
{
    const int idx = blockIdx.x * 256 + threadIdx.x;
    if (idx >= 2 * 150 * 1200) return;
    const int d  = idx / 180000;
    const int rm = idx % 180000;
    const int kk = rm / 1200;
    const int q  = rm % 1200;      // q = u*4 + gate
    const int u    = q >> 2;
    const int gate = q & 3;
    const int r    = gate * 300 + u;
    const float* w = d ? wb : wf;
    const float a = w[(size_t)r * HID + 2*kk];
    const float b = w[(size_t)r * HID + 2*kk + 1];
    wpk[idx] = pack_f16x2(a, b);
}

// ---------------------------------------------------------------------------
// Phase B: chunk-parallel LSTM (round-10: VGPR weight cache + BURN=64).
// 256 blocks (2 dir x 128 chunks), 320 threads (thread = unit).
// The 150-kk dot is 15 groups of 10. Groups 0-3 (27% of the 720 KB weight
// stream) are cached in registers ONCE before the step loop (160 VGPRs);
// groups 4-14 stream from L2 via the A/B ping-pong. Group-4 loads are issued
// before the cached compute so L2 latency hides under it. Accumulation order
// (groups 0..14, same dot2 sequence) is identical to round 2.
// ---------------------------------------------------------------------------
#define LDGRP(BUF, G)                                              \
    _Pragma("unroll")                                              \
    for (int j = 0; j < 10; j++){                                  \
        BUF[j] = wq[(size_t)((G)*10 + j) * 300];                   \
    }

#define CMPGRP(BUF, G)                                             \
    _Pragma("unroll")                                              \
    for (int j = 0; j < 10; j++){                                  \
        const uint32_t hp = hq[(G)*10 + j];                        \
        const uint4 w = BUF[j];                                    \
        ai = dot2f16(w.x, hp, ai);                                 \
        af = dot2f16(w.y, hp, af);                                 \
        ag = dot2f16(w.z, hp, ag);                                 \
        ao = dot2f16(w.w, hp, ao);                                 \
    }

__global__ __launch_bounds__(320, 1) void lstm_kernel(
    const uint32_t* __restrict__ wpk,
    const float* __restrict__ h0, const float* __restrict__ c0,
    const uint16_t* __restrict__ xg, uint32_t* __restrict__ hout)
{
    const int d = blockIdx.x >> 7;
    const int c = blockIdx.x & (NCHK - 1);
    const int tid = threadIdx.x;
    const int u = tid;
    const bool act = tid < HID;

    // h state as packed f16, double-buffered
    __shared__ __align__(8) uint16_t hbuf16[2][HID + 4];

    const int burn   = (d == 0) ? (c == 0 ? 0 : BURN) : (c == NCHK-1 ? 0 : BURN);
    const int nsteps = CHK + burn;
    int p = (d == 0) ? (c*CHK - burn) : ((c+1)*CHK - 1 + burn);

    float cst = 0.f;
    if (act){
        if (burn == 0){ cst = c0[d*HID + u]; hbuf16[0][u] = f16_bits(h0[d*HID + u]); }
        else          { hbuf16[0][u] = 0; }
    }
    __syncthreads();

    const uint32_t* wd  = wpk + (size_t)d * 150 * 1200;
    const uint4*    wq  = ((const uint4*)wd) + u;   // this unit's gate quad; stride 300 uint4 per kk
    const uint16_t* xgd = xg + (size_t)d * SEQ * G4;

    // ---- one-time VGPR weight cache: groups 0-3 (40 kk, 160 VGPRs) ----
    uint4 W0[10], W1[10], W2[10], W3[10];
    if (act){
        LDGRP(W0, 0)
        LDGRP(W1, 1)
        LDGRP(W2, 2)
        LDGRP(W3, 3)
    }

    uint16_t x0=0, x1=0, x2=0, x3=0;
    if (act){
        const uint16_t* xp = xgd + (size_t)p * G4 + u;
        x0 = xp[0]; x1 = xp[300]; x2 = xp[600]; x3 = xp[900];
    }

    #pragma unroll 1
    for (int i = 0; i < nsteps; i++){
        const int cur = i & 1;
        const int pn  = (d == 0) ? (p + 1) : (p - 1);
        const int pnc = (pn < 0) ? 0 : (pn >= SEQ ? SEQ-1 : pn);

        float ai = f16_to_f32(x0);
        float af = f16_to_f32(x1);
        float ag = f16_to_f32(x2);
        float ao = f16_to_f32(x3);

        // prefetch next step's xg (HBM latency hidden under this step's dot)
        uint16_t n0=0, n1=0, n2=0, n3=0;
        if (act){
            const uint16_t* xp = xgd + (size_t)pnc * G4 + u;
            n0 = xp[0]; n1 = xp[300]; n2 = xp[600]; n3 = xp[900];
        }

        if (act){
            const uint32_t* hq = (const uint32_t*)hbuf16[cur];
            uint4 A[10], B[10];

            LDGRP(A, 4)                    // issue first streamed group early
            CMPGRP(W0, 0)                  // cached compute hides L2 latency
            CMPGRP(W1, 1)
            CMPGRP(W2, 2)
            CMPGRP(W3, 3)
            #pragma unroll 1
            for (int pp = 0; pp < 5; pp++){
                const int g0 = 4 + 2*pp, g1 = 5 + 2*pp, g2 = 6 + 2*pp;
                LDGRP(B, g1)               // loads for g1 in flight...
                CMPGRP(A, g0)              // ...while computing g0
                LDGRP(A, g2)               // loads for g2 in flight...
                CMPGRP(B, g1)              // ...while computing g1
            }
            CMPGRP(A, 14)                  // final group

            const float gi = sigmoidf_(ai);
            const float gf = sigmoidf_(af);
            const float gg = tanhf_fast(ag);
            const float go = sigmoidf_(ao);
            cst = gf * cst + gi * gg;
            hbuf16[cur ^ 1][u] = f16_bits(go * tanhf_fast(cst));
        }
        __syncthreads();

        if (i >= burn && tid < 150){
            const uint32_t* hn = (const uint32_t*)hbuf16[cur ^ 1];
            hout[((size_t)d * SEQ + p) * 150 + tid] = hn[tid];
        }
        p = pn;
        x0 = n0; x1 = n1; x2 = n2; x3 = n3;
    }
}

// ---------------------------------------------------------------------------
// Phase C: feats[t][j] = [hf,hb] @ w_tag.T + b_tag. 256 blocks x 256 thr.
// ---------------------------------------------------------------------------
__global__ __launch_bounds__(256) void feats_kernel(
    const uint32_t* __restrict__ hout, const float* __restrict__ w_tag,
    const float* __restrict__ b_tag, float* __restrict__ feats)
{
    const int tl = threadIdx.x & 63;
    const int jg = threadIdx.x >> 6;
    const int t  = blockIdx.x * 64 + tl;
    float acc[5] = {0.f,0.f,0.f,0.f,0.f};
    #pragma unroll 1
    for (int dd = 0; dd < 2; dd++){
        const uint32_t* hp = hout + ((size_t)dd * SEQ + t) * 150;
        #pragma unroll 1
        for (int kw = 0; kw < 150; kw++){
            const uint32_t pk = hp[kw];
            const float hl = f16_to_f32((uint16_t)(pk & 0xffffu));
            const float hh = f16_to_f32((uint16_t)(pk >> 16));
            #pragma unroll
            for (int jj = 0; jj < 5; jj++){
                const float* wrow = w_tag + (size_t)(jg*5 + jj) * 600 + dd*300 + 2*kw;
                acc[jj] += hl * wrow[0] + hh * wrow[1];
            }
        }
    }
    #pragma unroll
    for (int jj = 0; jj < 5; jj++)
        feats[(size_t)t * NTAG + jg*5 + jj] = acc[jj] + b_tag[jg*5 + jj];
}

// ---------------------------------------------------------------------------
// K1: per-chunk tropical (max-plus) matrix F_c. 64 blocks x 512 thr.
// ---------------------------------------------------------------------------
__global__ __launch_bounds__(512) void k1_chunkmat(
    const float* __restrict__ feats, const float* __restrict__ trans, float* __restrict__ Fc)
{
    const int c = blockIdx.x;
    const int tid = threadIdx.x;
    __shared__ float fl[CH * NTAG];
    __shared__ float M[2][NTAG * NTAG];
    for (int i = tid; i < CH*NTAG; i += 512) fl[i] = feats[(size_t)c * CH * NTAG + i];
    const int j = tid / NTAG, p = tid % NTAG;
    float tr[NTAG];
    if (tid < 400){
        #pragma unroll
        for (int q = 0; q < NTAG; q++) tr[q] = trans[j*NTAG + q];
        M[0][tid] = (j == p) ? 0.f : -1e30f;
    }
    __syncthreads();
    #pragma unroll 1
    for (int t = 0; t < CH; t++){
        const int cur = t & 1, nxt = cur ^ 1;
        if (tid < 400){
            float best = -1e38f;
            #pragma unroll
            for (int q = 0; q < NTAG; q++)
                best = fmaxf(best, tr[q] + M[cur][q*NTAG + p]);
            M[nxt][tid] = best + fl[t*NTAG + j];
        }
        __syncthreads();
    }
    if (tid < 400) Fc[(size_t)c * 400 + tid] = M[CH & 1][tid];
}

// K2: sequential scan of 64 chunk matrices -> fv at each chunk start + score.
__global__ __launch_bounds__(64) void k2_scan(
    const float* __restrict__ Fc, const float* __restrict__ trans,
    float* __restrict__ fvb, float* __restrict__ score_out, int* __restrict__ bestbuf)
{
    const int j = threadIdx.x;
    const bool act = j < NTAG;
    float fv = (j == START) ? 0.f : NEGV;
    #pragma unroll 1
    for (int c = 0; c < NC; c++){
        if (act) fvb[c*NTAG + j] = fv;
        float best = -1e38f;
        #pragma unroll
        for (int q = 0; q < NTAG; q++){
            const float fq = __shfl(fv, q, 64);
            if (act) best = fmaxf(best, Fc[(size_t)c*400 + j*NTAG + q] + fq);
        }
        fv = act ? best : NEGV;
    }
    const float term = act ? (fv + trans[STOPT*NTAG + j]) : -1e38f;
    float bs = -1e38f; int bi = 0;
    #pragma unroll
    for (int q = 0; q < NTAG; q++){
        const float v = __shfl(term, q, 64);
        if (v > bs){ bs = v; bi = q; }
    }
    if (j == 0){ score_out[0] = bs; bestbuf[0] = bi; }
}

// K3: per-chunk re-walk -> backpointers (global) + chunk backtrace map mu_c.
__global__ __launch_bounds__(64) void k3_bp(
    const float* __restrict__ feats, const float* __restrict__ trans,
    const float* __restrict__ fvb, uint8_t* __restrict__ bps, int* __restrict__ mu)
{
    const int c = blockIdx.x;
    const int j = threadIdx.x;
    const bool act = j < NTAG;
    __shared__ float fl[CH * NTAG];
    __shared__ uint8_t bp[CH * NTAG];
    for (int i = j; i < CH*NTAG; i += 64) fl[i] = feats[(size_t)c * CH * NTAG + i];
    float tr[NTAG];
    if (act){
        #pragma unroll
        for (int q = 0; q < NTAG; q++) tr[q] = trans[j*NTAG + q];
    }
    float fv = act ? fvb[c*NTAG + j] : NEGV;
    __syncthreads();
    #pragma unroll 1
    for (int t = 0; t < CH; t++){
        float best = -1e38f; int bi = 0;
        #pragma unroll
        for (int q = 0; q < NTAG; q++){
            const float fq = __shfl(fv, q, 64);
            if (act){
                const float v = tr[q] + fq;
                if (v > best){ best = v; bi = q; }   // strict > : first max (argmax semantics)
            }
        }
        if (act) bp[t*NTAG + j] = (uint8_t)bi;
        fv = act ? (best + fl[t*NTAG + j]) : NEGV;
    }
    __syncthreads();
    int m = act ? j : 0;
    #pragma unroll 1
    for (int t = CH-1; t >= 0; t--){
        if (act) m = bp[t*NTAG + m];
    }
    if (act) mu[c*NTAG + j] = m;
    for (int i = j; i < CH*NTAG; i += 64) bps[(size_t)c * CH * NTAG + i] = bp[i];
}

// K4: chunk-boundary tags (tiny sequential).
__global__ void k4_tags(const int* __restrict__ mu, const int* __restrict__ bestbuf,
                        int* __restrict__ tagend)
{
    if (threadIdx.x == 0 && blockIdx.x == 0){
        int g = bestbuf[0];
        tagend[NC-1] = g;
        for (int c = NC-1; c >= 1; c--){ g = mu[c*NTAG + g]; tagend[c-1] = g; }
    }
}

// K5: per-chunk path fill -> d_out[1..SEQ] as f32 tags.
__global__ __launch_bounds__(64) void k5_path(
    const uint8_t* __restrict__ bps, const int* __restrict__ tagend, float* __restrict__ outpath)
{
    const int c = blockIdx.x;
    const int tid = threadIdx.x;
    __shared__ uint8_t bp[CH * NTAG];
    __shared__ float pl[CH];
    for (int i = tid; i < CH*NTAG; i += 64) bp[i] = bps[(size_t)c * CH * NTAG + i];
    __syncthreads();
    if (tid == 0){
        int g = tagend[c];
        pl[CH-1] = (float)g;
        for (int t = CH-1; t >= 1; t--){ g = bp[t*NTAG + g]; pl[t-1] = (float)g; }
    }
    __syncthreads();
    for (int i = tid; i < CH; i += 64) outpath[(size_t)c * CH + i] = pl[i];
}

// ---------------------------------------------------------------------------
extern "C" void kernel_launch(void* const* d_in, const int* in_sizes, int n_in,
                              void* d_out, int out_size, void* d_ws, size_t ws_size,
                              hipStream_t stream)
{
    const int*   sent    = (const int*)  d_in[0];
    const float* embed   = (const float*)d_in[1];
    const float* w_ih_f  = (const float*)d_in[2];
    const float* w_hh_f  = (const float*)d_in[3];
    const float* b_ih_f  = (const float*)d_in[4];
    const float* b_hh_f  = (const float*)d_in[5];
    const float* w_ih_b  = (const float*)d_in[6];
    const float* w_hh_b  = (const float*)d_in[7];
    const float* b_ih_b  = (const float*)d_in[8];
    const float* b_hh_b  = (const float*)d_in[9];
    const float* h0      = (const float*)d_in[10];
    const float* c0      = (const float*)d_in[11];
    const float* w_tag   = (const float*)d_in[12];
    const float* b_tag   = (const float*)d_in[13];
    const float* trans   = (const float*)d_in[14];
    float* out = (float*)d_out;

    char* ws = (char*)d_ws;
    size_t off = 0;
    auto alloc = [&](size_t bytes)->char*{
        char* p = ws + off; off += (bytes + 255) & ~(size_t)255; return p;
    };
    uint16_t* xg     = (uint16_t*)alloc(2ull * SEQ * G4 * 2);     // 78.6 MB
    uint32_t* hout   = (uint32_t*)alloc(2ull * SEQ * 150 * 4);    // 19.7 MB
    float*    feats  = (float*)   alloc((size_t)SEQ * NTAG * 4);  // 1.3 MB
    uint32_t* wpk    = (uint32_t*)alloc(2ull * 150 * 1200 * 4);   // 1.44 MB
    float*    Fc     = (float*)   alloc((size_t)NC * 400 * 4);
    float*    fvb    = (float*)   alloc((size_t)NC * NTAG * 4);
    uint8_t*  bps    = (uint8_t*) alloc((size_t)SEQ * NTAG);
    int*      mu     = (int*)     alloc((size_t)NC * NTAG * 4);
    int*      tagend = (int*)     alloc((size_t)NC * 4);
    int*      bestbuf= (int*)     alloc(256);

    hipLaunchKernelGGL(xg_kernel, dim3(1024), dim3(256), 0, stream,
                       sent, embed, w_ih_f, b_ih_f, b_hh_f, w_ih_b, b_ih_b, b_hh_b, xg);
    hipLaunchKernelGGL(prep_w, dim3((2*150*1200 + 255)/256), dim3(256), 0, stream,
                       w_hh_f, w_hh_b, wpk);
    hipLaunchKernelGGL(lstm_kernel, dim3(2 * NCHK), dim3(320), 0, stream,
                       wpk, h0, c0, xg, hout);
    hipLaunchKernelGGL(feats_kernel, dim3(256), dim3(256), 0, stream,
                       hout, w_tag, b_tag, feats);
    hipLaunchKernelGGL(k1_chunkmat, dim3(NC), dim3(512), 0, stream, feats, trans, Fc);
    hipLaunchKernelGGL(k2_scan, dim3(1), dim3(64), 0, stream, Fc, trans, fvb, out, bestbuf);
    hipLaunchKernelGGL(k3_bp, dim3(NC), dim3(64), 0, stream, feats, trans, fvb, bps, mu);
    hipLaunchKernelGGL(k4_tags, dim3(1), dim3(64), 0, stream, mu, bestbuf, tagend);
    hipLaunchKernelGGL(k5_path, dim3(NC), dim3(64), 0, stream, bps, tagend, out + 1);
}

// Round 5
// 1866.356 us; speedup vs baseline: 1.5545x; 1.5545x over previous
//
#include <hip/hip_runtime.h>
#include <stdint.h>

#define SEQ   16384
#define EMB   50
#define HID   300
#define G4    1200
#define NTAG  20
#define START 18
#define STOPT 19
#define NEGV  -10000.0f
#define NC    64
#define CH    256   // SEQ / NC (viterbi chunking)

#define CHK   128   // LSTM chunk length
#define NCHK  128   // chunks per direction
#define BURN  64    // burn-in steps (f^64 <= f16 eps; absmax unchanged 96->64 in r4)
#define NLG   3     // weight groups cached in LDS (30 kk = 144 KB)

__device__ __forceinline__ float rcp_fast(float x){ return __builtin_amdgcn_rcpf(x); }
__device__ __forceinline__ float sigmoidf_(float x){ return rcp_fast(1.f + __expf(-x)); }
__device__ __forceinline__ float tanhf_fast(float x){
    float e = __expf(-2.f * fabsf(x));
    float r = (1.f - e) * rcp_fast(1.f + e);
    return copysignf(r, x);
}

// ---- f16 helpers (recurrent path is f16: more mantissa than bf16) ----------
typedef _Float16 half2v __attribute__((ext_vector_type(2)));

__device__ __forceinline__ uint16_t f16_bits(float x){
    union { _Float16 h; uint16_t u; } v; v.h = (_Float16)x; return v.u;
}
__device__ __forceinline__ float f16_to_f32(uint16_t u){
    union { _Float16 h; uint16_t u; } v; v.u = u; return (float)v.h;
}
__device__ __forceinline__ uint32_t pack_f16x2(float a, float b){
    return (uint32_t)f16_bits(a) | ((uint32_t)f16_bits(b) << 16);
}
// acc += w.lo*h.lo + w.hi*h.hi  (one v_dot2_f32_f16 when available)
__device__ __forceinline__ float dot2f16(uint32_t w, uint32_t h, float acc){
    union { uint32_t u; half2v v; } a, b; a.u = w; b.u = h;
#if __has_builtin(__builtin_amdgcn_fdot2)
    return __builtin_amdgcn_fdot2(a.v, b.v, acc, false);
#else
    acc = fmaf((float)a.v.x, (float)b.v.x, acc);
    return fmaf((float)a.v.y, (float)b.v.y, acc);
#endif
}

// ---------------------------------------------------------------------------
// Phase A: xg[d][t][1200] (f16) = emb[sent[t]] @ w_ih_d.T + b_ih_d + b_hh_d
// ---------------------------------------------------------------------------
__global__ __launch_bounds__(256) void xg_kernel(
    const int* __restrict__ sent, const float* __restrict__ embed,
    const float* __restrict__ w_ih_f, const float* __restrict__ b_ih_f, const float* __restrict__ b_hh_f,
    const float* __restrict__ w_ih_b, const float* __restrict__ b_ih_b, const float* __restrict__ b_hh_b,
    uint16_t* __restrict__ xg)
{
    const int tg = blockIdx.x / 16;
    const int rg = blockIdx.x % 16;
    const int d  = rg / 8;
    const int rbase = (rg % 8) * 150;
    const int t = tg * 256 + threadIdx.x;

    const float* w_ih = d ? w_ih_b : w_ih_f;
    const float* b_ih = d ? b_ih_b : b_ih_f;
    const float* b_hh = d ? b_hh_b : b_hh_f;

    const int idx = sent[t];
    float e[EMB];
    const float* ep = embed + (size_t)idx * EMB;
    #pragma unroll
    for (int c = 0; c < EMB; c += 2){
        float2 v = *(const float2*)(ep + c);
        e[c] = v.x; e[c+1] = v.y;
    }
    uint16_t* outp = xg + ((size_t)d * SEQ + t) * G4 + rbase;
    #pragma unroll 1
    for (int rr = 0; rr < 150; rr += 2){
        float acc[2];
        #pragma unroll
        for (int k = 0; k < 2; k++){
            const int row = rbase + rr + k;
            const float* wr = w_ih + (size_t)row * EMB;
            float a0 = 0.f, a1 = 0.f;
            #pragma unroll
            for (int c = 0; c < EMB; c += 2){
                a0 += e[c]   * wr[c];
                a1 += e[c+1] * wr[c+1];
            }
            acc[k] = a0 + a1 + b_ih[row] + b_hh[row];
        }
        *(uint32_t*)(outp + rr) = pack_f16x2(acc[0], acc[1]);
    }
}

// ---------------------------------------------------------------------------
// Prep: pack w_hh (f32 [1200][300]) -> wpk[d][kk][u][gate] (f16 pairs, k=2kk).
// Gate-interleaved: the LSTM loads one dwordx4 per (u,kk); coalesced per wave.
// ---------------------------------------------------------------------------
__global__ __launch_bounds__(256) void prep_w(
    const float* __restrict__ wf, const float* __restrict__ wb, uint32_t* __restrict__ wpk)
{
    const int idx = blockIdx.x * 256 + threadIdx.x;
    if (idx >= 2 * 150 * 1200) return;
    const int d  = idx / 180000;
    const int rm = idx % 180000;
    const int kk = rm / 1200;
    const int q  = rm % 1200;      // q = u*4 + gate
    const int u    = q >> 2;
    const int gate = q & 3;
    const int r    = gate * 300 + u;
    const float* w = d ? wb : wf;
    const float a = w[(size_t)r * HID + 2*kk];
    const float b = w[(size_t)r * HID + 2*kk + 1];
    wpk[idx] = pack_f16x2(a, b);
}

// ---------------------------------------------------------------------------
// Phase B: chunk-parallel LSTM (round-11: LDS weight cache + BURN=64).
// 256 blocks (2 dir x 128 chunks), 320 threads (thread = unit).
// 150-kk dot = 15 groups of 10. Groups 0-2 (144 KB) live in LDS, loaded once
// -- LDS read port (128 B/cyc/CU) runs in parallel with the L2 stream
// (~50 B/cyc/CU), cutting streamed bytes 20% (720->576 KB/step). Groups 3-14
// stream via the A/B ping-pong; group-3 loads are issued before the cached
// compute so their L2 latency hides under 120 LDS-fed dot2s. Accumulation
// order (groups 0..14) identical to round 2. No big VGPR arrays (r4 spill
// lesson: allocator caps at 128 VGPRs here).
// ---------------------------------------------------------------------------
#define LDGRP(BUF, G)                                              \
    _Pragma("unroll")                                              \
    for (int j = 0; j < 10; j++){                                  \
        BUF[j] = wq[(size_t)((G)*10 + j) * 300];                   \
    }

#define CMPGRP(BUF, G)                                             \
    _Pragma("unroll")                                              \
    for (int j = 0; j < 10; j++){                                  \
        const uint32_t hp = hq[(G)*10 + j];                        \
        const uint4 w = BUF[j];                                    \
        ai = dot2f16(w.x, hp, ai);                                 \
        af = dot2f16(w.y, hp, af);                                 \
        ag = dot2f16(w.z, hp, ag);                                 \
        ao = dot2f16(w.w, hp, ao);                                 \
    }

#define CMPGRP_L(G)                                                \
    _Pragma("unroll")                                              \
    for (int j = 0; j < 10; j++){                                  \
        const uint32_t hp = hq[(G)*10 + j];                        \
        const uint4 w = *(const uint4*)(wlds + (size_t)((G)*10 + j) * 1200 + 4*u); \
        ai = dot2f16(w.x, hp, ai);                                 \
        af = dot2f16(w.y, hp, af);                                 \
        ag = dot2f16(w.z, hp, ag);                                 \
        ao = dot2f16(w.w, hp, ao);                                 \
    }

__global__ __launch_bounds__(320, 1) void lstm_kernel(
    const uint32_t* __restrict__ wpk,
    const float* __restrict__ h0, const float* __restrict__ c0,
    const uint16_t* __restrict__ xg, uint32_t* __restrict__ hout)
{
    const int d = blockIdx.x >> 7;
    const int c = blockIdx.x & (NCHK - 1);
    const int tid = threadIdx.x;
    const int u = tid;
    const bool act = tid < HID;

    // LDS: weight cache (groups 0-2, 144 KB) + h double-buffer (1.2 KB)
    __shared__ __align__(16) uint32_t wlds[NLG * 10 * 1200];
    __shared__ __align__(8) uint16_t hbuf16[2][HID + 4];

    const int burn   = (d == 0) ? (c == 0 ? 0 : BURN) : (c == NCHK-1 ? 0 : BURN);
    const int nsteps = CHK + burn;
    int p = (d == 0) ? (c*CHK - burn) : ((c+1)*CHK - 1 + burn);

    const uint32_t* wd  = wpk + (size_t)d * 150 * 1200;
    const uint4*    wq  = ((const uint4*)wd) + u;   // this unit's gate quad; stride 300 uint4 per kk
    const uint16_t* xgd = xg + (size_t)d * SEQ * G4;

    // one-time LDS weight cache fill (first 30 kk = 36000 dwords = 144 KB)
    for (int idx = tid; idx < NLG * 10 * 1200; idx += 320) wlds[idx] = wd[idx];

    float cst = 0.f;
    if (act){
        if (burn == 0){ cst = c0[d*HID + u]; hbuf16[0][u] = f16_bits(h0[d*HID + u]); }
        else          { hbuf16[0][u] = 0; }
    }
    __syncthreads();

    uint16_t x0=0, x1=0, x2=0, x3=0;
    if (act){
        const uint16_t* xp = xgd + (size_t)p * G4 + u;
        x0 = xp[0]; x1 = xp[300]; x2 = xp[600]; x3 = xp[900];
    }

    #pragma unroll 1
    for (int i = 0; i < nsteps; i++){
        const int cur = i & 1;
        const int pn  = (d == 0) ? (p + 1) : (p - 1);
        const int pnc = (pn < 0) ? 0 : (pn >= SEQ ? SEQ-1 : pn);

        float ai = f16_to_f32(x0);
        float af = f16_to_f32(x1);
        float ag = f16_to_f32(x2);
        float ao = f16_to_f32(x3);

        // prefetch next step's xg (HBM latency hidden under this step's dot)
        uint16_t n0=0, n1=0, n2=0, n3=0;
        if (act){
            const uint16_t* xp = xgd + (size_t)pnc * G4 + u;
            n0 = xp[0]; n1 = xp[300]; n2 = xp[600]; n3 = xp[900];
        }

        if (act){
            const uint32_t* hq = (const uint32_t*)hbuf16[cur];
            uint4 A[10], B[10];

            LDGRP(A, 3)                    // first streamed group in flight...
            CMPGRP_L(0)                    // ...under 120 LDS-fed dot2s
            CMPGRP_L(1)
            CMPGRP_L(2)
            #pragma unroll 1
            for (int pp = 0; pp < 5; pp++){
                const int g0 = 3 + 2*pp, g1 = g0 + 1, g2 = g0 + 2;
                LDGRP(B, g1)               // loads for g1 in flight...
                CMPGRP(A, g0)              // ...while computing g0
                LDGRP(A, g2)               // loads for g2 in flight...
                CMPGRP(B, g1)              // ...while computing g1
            }
            LDGRP(B, 14)
            CMPGRP(A, 13)
            CMPGRP(B, 14)

            const float gi = sigmoidf_(ai);
            const float gf = sigmoidf_(af);
            const float gg = tanhf_fast(ag);
            const float go = sigmoidf_(ao);
            cst = gf * cst + gi * gg;
            hbuf16[cur ^ 1][u] = f16_bits(go * tanhf_fast(cst));
        }
        __syncthreads();

        if (i >= burn && tid < 150){
            const uint32_t* hn = (const uint32_t*)hbuf16[cur ^ 1];
            hout[((size_t)d * SEQ + p) * 150 + tid] = hn[tid];
        }
        p = pn;
        x0 = n0; x1 = n1; x2 = n2; x3 = n3;
    }
}

// ---------------------------------------------------------------------------
// Phase C: feats[t][j] = [hf,hb] @ w_tag.T + b_tag. 256 blocks x 256 thr.
// ---------------------------------------------------------------------------
__global__ __launch_bounds__(256) void feats_kernel(
    const uint32_t* __restrict__ hout, const float* __restrict__ w_tag,
    const float* __restrict__ b_tag, float* __restrict__ feats)
{
    const int tl = threadIdx.x & 63;
    const int jg = threadIdx.x >> 6;
    const int t  = blockIdx.x * 64 + tl;
    float acc[5] = {0.f,0.f,0.f,0.f,0.f};
    #pragma unroll 1
    for (int dd = 0; dd < 2; dd++){
        const uint32_t* hp = hout + ((size_t)dd * SEQ + t) * 150;
        #pragma unroll 1
        for (int kw = 0; kw < 150; kw++){
            const uint32_t pk = hp[kw];
            const float hl = f16_to_f32((uint16_t)(pk & 0xffffu));
            const float hh = f16_to_f32((uint16_t)(pk >> 16));
            #pragma unroll
            for (int jj = 0; jj < 5; jj++){
                const float* wrow = w_tag + (size_t)(jg*5 + jj) * 600 + dd*300 + 2*kw;
                acc[jj] += hl * wrow[0] + hh * wrow[1];
            }
        }
    }
    #pragma unroll
    for (int jj = 0; jj < 5; jj++)
        feats[(size_t)t * NTAG + jg*5 + jj] = acc[jj] + b_tag[jg*5 + jj];
}

// ---------------------------------------------------------------------------
// K1: per-chunk tropical (max-plus) matrix F_c. 64 blocks x 512 thr.
// ---------------------------------------------------------------------------
__global__ __launch_bounds__(512) void k1_chunkmat(
    const float* __restrict__ feats, const float* __restrict__ trans, float* __restrict__ Fc)
{
    const int c = blockIdx.x;
    const int tid = threadIdx.x;
    __shared__ float fl[CH * NTAG];
    __shared__ float M[2][NTAG * NTAG];
    for (int i = tid; i < CH*NTAG; i += 512) fl[i] = feats[(size_t)c * CH * NTAG + i];
    const int j = tid / NTAG, p = tid % NTAG;
    float tr[NTAG];
    if (tid < 400){
        #pragma unroll
        for (int q = 0; q < NTAG; q++) tr[q] = trans[j*NTAG + q];
        M[0][tid] = (j == p) ? 0.f : -1e30f;
    }
    __syncthreads();
    #pragma unroll 1
    for (int t = 0; t < CH; t++){
        const int cur = t & 1, nxt = cur ^ 1;
        if (tid < 400){
            float best = -1e38f;
            #pragma unroll
            for (int q = 0; q < NTAG; q++)
                best = fmaxf(best, tr[q] + M[cur][q*NTAG + p]);
            M[nxt][tid] = best + fl[t*NTAG + j];
        }
        __syncthreads();
    }
    if (tid < 400) Fc[(size_t)c * 400 + tid] = M[CH & 1][tid];
}

// K2: sequential scan of 64 chunk matrices -> fv at each chunk start + score.
__global__ __launch_bounds__(64) void k2_scan(
    const float* __restrict__ Fc, const float* __restrict__ trans,
    float* __restrict__ fvb, float* __restrict__ score_out, int* __restrict__ bestbuf)
{
    const int j = threadIdx.x;
    const bool act = j < NTAG;
    float fv = (j == START) ? 0.f : NEGV;
    #pragma unroll 1
    for (int c = 0; c < NC; c++){
        if (act) fvb[c*NTAG + j] = fv;
        float best = -1e38f;
        #pragma unroll
        for (int q = 0; q < NTAG; q++){
            const float fq = __shfl(fv, q, 64);
            if (act) best = fmaxf(best, Fc[(size_t)c*400 + j*NTAG + q] + fq);
        }
        fv = act ? best : NEGV;
    }
    const float term = act ? (fv + trans[STOPT*NTAG + j]) : -1e38f;
    float bs = -1e38f; int bi = 0;
    #pragma unroll
    for (int q = 0; q < NTAG; q++){
        const float v = __shfl(term, q, 64);
        if (v > bs){ bs = v; bi = q; }
    }
    if (j == 0){ score_out[0] = bs; bestbuf[0] = bi; }
}

// K3: per-chunk re-walk -> backpointers (global) + chunk backtrace map mu_c.
__global__ __launch_bounds__(64) void k3_bp(
    const float* __restrict__ feats, const float* __restrict__ trans,
    const float* __restrict__ fvb, uint8_t* __restrict__ bps, int* __restrict__ mu)
{
    const int c = blockIdx.x;
    const int j = threadIdx.x;
    const bool act = j < NTAG;
    __shared__ float fl[CH * NTAG];
    __shared__ uint8_t bp[CH * NTAG];
    for (int i = j; i < CH*NTAG; i += 64) fl[i] = feats[(size_t)c * CH * NTAG + i];
    float tr[NTAG];
    if (act){
        #pragma unroll
        for (int q = 0; q < NTAG; q++) tr[q] = trans[j*NTAG + q];
    }
    float fv = act ? fvb[c*NTAG + j] : NEGV;
    __syncthreads();
    #pragma unroll 1
    for (int t = 0; t < CH; t++){
        float best = -1e38f; int bi = 0;
        #pragma unroll
        for (int q = 0; q < NTAG; q++){
            const float fq = __shfl(fv, q, 64);
            if (act){
                const float v = tr[q] + fq;
                if (v > best){ best = v; bi = q; }   // strict > : first max (argmax semantics)
            }
        }
        if (act) bp[t*NTAG + j] = (uint8_t)bi;
        fv = act ? (best + fl[t*NTAG + j]) : NEGV;
    }
    __syncthreads();
    int m = act ? j : 0;
    #pragma unroll 1
    for (int t = CH-1; t >= 0; t--){
        if (act) m = bp[t*NTAG + m];
    }
    if (act) mu[c*NTAG + j] = m;
    for (int i = j; i < CH*NTAG; i += 64) bps[(size_t)c * CH * NTAG + i] = bp[i];
}

// K4: chunk-boundary tags (tiny sequential).
__global__ void k4_tags(const int* __restrict__ mu, const int* __restrict__ bestbuf,
                        int* __restrict__ tagend)
{
    if (threadIdx.x == 0 && blockIdx.x == 0){
        int g = bestbuf[0];
        tagend[NC-1] = g;
        for (int c = NC-1; c >= 1; c--){ g = mu[c*NTAG + g]; tagend[c-1] = g; }
    }
}

// K5: per-chunk path fill -> d_out[1..SEQ] as f32 tags.
__global__ __launch_bounds__(64) void k5_path(
    const uint8_t* __restrict__ bps, const int* __restrict__ tagend, float* __restrict__ outpath)
{
    const int c = blockIdx.x;
    const int tid = threadIdx.x;
    __shared__ uint8_t bp[CH * NTAG];
    __shared__ float pl[CH];
    for (int i = tid; i < CH*NTAG; i += 64) bp[i] = bps[(size_t)c * CH * NTAG + i];
    __syncthreads();
    if (tid == 0){
        int g = tagend[c];
        pl[CH-1] = (float)g;
        for (int t = CH-1; t >= 1; t--){ g = bp[t*NTAG + g]; pl[t-1] = (float)g; }
    }
    __syncthreads();
    for (int i = tid; i < CH; i += 64) outpath[(size_t)c * CH + i] = pl[i];
}

// ---------------------------------------------------------------------------
extern "C" void kernel_launch(void* const* d_in, const int* in_sizes, int n_in,
                              void* d_out, int out_size, void* d_ws, size_t ws_size,
                              hipStream_t stream)
{
    const int*   sent    = (const int*)  d_in[0];
    const float* embed   = (const float*)d_in[1];
    const float* w_ih_f  = (const float*)d_in[2];
    const float* w_hh_f  = (const float*)d_in[3];
    const float* b_ih_f  = (const float*)d_in[4];
    const float* b_hh_f  = (const float*)d_in[5];
    const float* w_ih_b  = (const float*)d_in[6];
    const float* w_hh_b  = (const float*)d_in[7];
    const float* b_ih_b  = (const float*)d_in[8];
    const float* b_hh_b  = (const float*)d_in[9];
    const float* h0      = (const float*)d_in[10];
    const float* c0      = (const float*)d_in[11];
    const float* w_tag   = (const float*)d_in[12];
    const float* b_tag   = (const float*)d_in[13];
    const float* trans   = (const float*)d_in[14];
    float* out = (float*)d_out;

    char* ws = (char*)d_ws;
    size_t off = 0;
    auto alloc = [&](size_t bytes)->char*{
        char* p = ws + off; off += (bytes + 255) & ~(size_t)255; return p;
    };
    uint16_t* xg     = (uint16_t*)alloc(2ull * SEQ * G4 * 2);     // 78.6 MB
    uint32_t* hout   = (uint32_t*)alloc(2ull * SEQ * 150 * 4);    // 19.7 MB
    float*    feats  = (float*)   alloc((size_t)SEQ * NTAG * 4);  // 1.3 MB
    uint32_t* wpk    = (uint32_t*)alloc(2ull * 150 * 1200 * 4);   // 1.44 MB
    float*    Fc     = (float*)   alloc((size_t)NC * 400 * 4);
    float*    fvb    = (float*)   alloc((size_t)NC * NTAG * 4);
    uint8_t*  bps    = (uint8_t*) alloc((size_t)SEQ * NTAG);
    int*      mu     = (int*)     alloc((size_t)NC * NTAG * 4);
    int*      tagend = (int*)     alloc((size_t)NC * 4);
    int*      bestbuf= (int*)     alloc(256);

    hipLaunchKernelGGL(xg_kernel, dim3(1024), dim3(256), 0, stream,
                       sent, embed, w_ih_f, b_ih_f, b_hh_f, w_ih_b, b_ih_b, b_hh_b, xg);
    hipLaunchKernelGGL(prep_w, dim3((2*150*1200 + 255)/256), dim3(256), 0, stream,
                       w_hh_f, w_hh_b, wpk);
    hipLaunchKernelGGL(lstm_kernel, dim3(2 * NCHK), dim3(320), 0, stream,
                       wpk, h0, c0, xg, hout);
    hipLaunchKernelGGL(feats_kernel, dim3(256), dim3(256), 0, stream,
                       hout, w_tag, b_tag, feats);
    hipLaunchKernelGGL(k1_chunkmat, dim3(NC), dim3(512), 0, stream, feats, trans, Fc);
    hipLaunchKernelGGL(k2_scan, dim3(1), dim3(64), 0, stream, Fc, trans, fvb, out, bestbuf);
    hipLaunchKernelGGL(k3_bp, dim3(NC), dim3(64), 0, stream, feats, trans, fvb, bps, mu);
    hipLaunchKernelGGL(k4_tags, dim3(1), dim3(64), 0, stream, mu, bestbuf, tagend);
    hipLaunchKernelGGL(k5_path, dim3(NC), dim3(64), 0, stream, bps, tagend, out + 1);
}